// Round 6
// baseline (190.318 us; speedup 1.0000x reference)
//
#include <hip/hip_runtime.h>
#include <hip/hip_bf16.h>
#include <math.h>

#define H_  32
#define D_  4096
#define K_  128
#define V_  128
#define M_  8191     // prev cache length
#define MC_ 8192     // cache length after append
#define NCH_ 16      // proj d-chunks (256 d each)

typedef float f32x4 __attribute__((ext_vector_type(4)));

__device__ inline f32x4 ntload4(const float* p) {
    return __builtin_nontemporal_load((const f32x4*)p);
}
__device__ inline void ntstore4(float* p, f32x4 v) {
    __builtin_nontemporal_store(v, (f32x4*)p);
}

// sign-aware float atomic max (addr pre-initialized to -INF or valid float).
__device__ inline void atomicMaxF(float* addr, float v) {
    if (v >= 0.f) atomicMax((int*)addr, __float_as_int(v));
    else          atomicMin((unsigned int*)addr, __float_as_uint(v));
}

// ---------------------------------------------------------------------------
// Kernel A: q/k_new/v_new projection PARTIALS (non-atomic).
//   part[proj][h][chunk][k] = sum_{d in chunk} x[d] * W[h,d,k]
// grid (16 d-chunks of 256, 32 heads, 3 projections), block 256.
// Also initializes mx[h] = -INF (proj completes before kernel B's atomics).
// ---------------------------------------------------------------------------
__global__ void proj_kernel(const float* __restrict__ x,
                            const float* __restrict__ Wq,
                            const float* __restrict__ Wk,
                            const float* __restrict__ Wv,
                            float* __restrict__ part /* [3][H][NCH][K] */,
                            float* __restrict__ mx   /* [H] */) {
    const int chunk = blockIdx.x;   // 0..15, 256 d each
    const int h     = blockIdx.y;
    const int proj  = blockIdx.z;
    const float* W  = (proj == 0) ? Wq : ((proj == 1) ? Wk : Wv);

    const int t   = threadIdx.x;    // 256
    const int grp = t >> 5;         // 0..7
    const int cl  = t & 31;         // float4 column lane

    if (chunk == 0 && proj == 0 && t == 0) mx[h] = -INFINITY;

    __shared__ float xs[256];
    xs[t] = x[chunk * 256 + t];
    __syncthreads();

    const float* Wh = W + (size_t)h * D_ * K_ + (size_t)chunk * 256 * K_;

    f32x4 acc = {0.f, 0.f, 0.f, 0.f};
    #pragma unroll 4
    for (int r = grp; r < 256; r += 8) {
        const f32x4 v4 = ntload4(&Wh[(size_t)r * K_ + cl * 4]);
        acc += xs[r] * v4;
    }

    __shared__ float lds[8][K_];
    *(f32x4*)&lds[grp][cl * 4] = acc;
    __syncthreads();
    if (t < K_) {
        float s = 0.f;
        #pragma unroll
        for (int j = 0; j < 8; ++j) s += lds[j][t];
        part[((size_t)proj * H_ + h) * NCH_ * K_ + chunk * K_ + t] = s;
    }
}

// ---------------------------------------------------------------------------
// Kernel B: fused K-cache copy + logits + per-head running max.
// Reduces q (and, in the last chunk, k_new) from proj partials in LDS.
// Handles ALL 8192 rows; row M sources k_new from LDS.
// Also zeroes o[h,:] and S[h] (B completes before kernel D's atomics).
// grid (128 chunks of 64 rows, 32 heads), block 256 (8 half-wave groups).
// ---------------------------------------------------------------------------
__global__ void copyK_logits_kernel(const float* __restrict__ prev_K,
                                    const float* __restrict__ part,
                                    float* __restrict__ Kc,
                                    float* __restrict__ lg,
                                    float* __restrict__ mx /* [H] */,
                                    float* __restrict__ o  /* [H][V] */,
                                    float* __restrict__ S  /* [H] */) {
    const int chunk = blockIdx.x;
    const int h     = blockIdx.y;
    const int t     = threadIdx.x;
    const int grp   = t >> 5;       // 0..7: half-wave group
    const int cl    = t & 31;       // float4 column lane

    if (chunk == 0) {
        if (t < V_) o[h * V_ + t] = 0.f;
        if (t == 0) S[h] = 0.f;
    }

    __shared__ float qs[K_];
    __shared__ float kns[K_];
    if (t < K_) {
        const float* pq = part + (size_t)h * NCH_ * K_ + t;
        float s = 0.f;
        #pragma unroll
        for (int c = 0; c < NCH_; ++c) s += pq[c * K_];
        qs[t] = s;
    } else if (chunk == 127) {
        const int tt = t - K_;
        const float* pk = part + ((size_t)H_ + h) * NCH_ * K_ + tt;
        float s = 0.f;
        #pragma unroll
        for (int c = 0; c < NCH_; ++c) s += pk[c * K_];
        kns[tt] = s;
    }
    __syncthreads();

    const f32x4 q4 = *(const f32x4*)&qs[cl * 4];

    const float* Ksrc = prev_K + (size_t)h * M_ * K_;
    float*       Kd   = Kc     + (size_t)h * MC_ * K_;
    float*       L    = lg     + (size_t)h * MC_;

    __shared__ float pbuf[64][33];

    #pragma unroll
    for (int r = 0; r < 8; ++r) {
        const int ml = r * 8 + grp;          // local row 0..63
        const int m  = chunk * 64 + ml;
        f32x4 v4;
        if (m != M_) v4 = ntload4(&Ksrc[(size_t)m * K_ + cl * 4]);
        else         v4 = *(const f32x4*)&kns[cl * 4];
        ntstore4(&Kd[(size_t)m * K_ + cl * 4], v4);
        const f32x4 p4 = v4 * q4;
        pbuf[ml][cl] = p4.x + p4.y + p4.z + p4.w;
    }
    __syncthreads();

    __shared__ float rmax[64];
    if (t < 64) {
        float s = 0.f;
        #pragma unroll
        for (int j = 0; j < 32; ++j) s += pbuf[t][j];
        L[chunk * 64 + t] = s;
        rmax[t] = s;
    }
    __syncthreads();
    if (t == 0) {
        float mm = rmax[0];
        #pragma unroll
        for (int j = 1; j < 64; ++j) mm = fmaxf(mm, rmax[j]);
        atomicMaxF(&mx[h], mm);
    }
}

// ---------------------------------------------------------------------------
// Kernel D: fused V-cache copy + unnormalized exp-weighted sum + S accumulate.
//   o[h,v] += sum_m exp(l[m]-MX) * V[h,m,v];  S[h] += sum_m exp(l[m]-MX)
// Row M sources v_new (reduced from proj partials in LDS).
// Also zeroes y (D completes before kernel E's atomics).
// grid (128 chunks of 64 rows, 32 heads), block 256.
// ---------------------------------------------------------------------------
__global__ void copyV_out_kernel(const float* __restrict__ prev_V,
                                 const float* __restrict__ part,
                                 const float* __restrict__ lg,
                                 const float* __restrict__ mx,
                                 float* __restrict__ Vc,
                                 float* __restrict__ o /* [H][V] */,
                                 float* __restrict__ S /* [H] */,
                                 float* __restrict__ y /* [D] */) {
    const int chunk = blockIdx.x;
    const int h     = blockIdx.y;
    const int t     = threadIdx.x;
    const int grp   = t >> 5;
    const int cl    = t & 31;

    if (chunk == 0 && t < 128) y[h * 128 + t] = 0.f;

    __shared__ float vns[K_];
    if (chunk == 127 && t < K_) {
        const float* pv = part + ((size_t)2 * H_ + h) * NCH_ * K_ + t;
        float s = 0.f;
        #pragma unroll
        for (int c = 0; c < NCH_; ++c) s += pv[c * K_];
        vns[t] = s;
    }
    __syncthreads();

    const float MX = mx[h];
    const float* Vsrc = prev_V + (size_t)h * M_ * V_;
    float*       Vd   = Vc     + (size_t)h * MC_ * V_;
    const float* L    = lg     + (size_t)h * MC_;

    f32x4 acc = {0.f, 0.f, 0.f, 0.f};
    #pragma unroll
    for (int r = 0; r < 8; ++r) {
        const int m = chunk * 64 + r * 8 + grp;
        f32x4 v4;
        if (m != M_) v4 = ntload4(&Vsrc[(size_t)m * V_ + cl * 4]);
        else         v4 = *(const f32x4*)&vns[cl * 4];
        ntstore4(&Vd[(size_t)m * V_ + cl * 4], v4);
        const float e = __expf(L[m] - MX);
        acc += e * v4;
    }

    __shared__ float lds[8][V_];
    *(f32x4*)&lds[grp][cl * 4] = acc;

    __shared__ float rsum[64];
    if (t < 64) rsum[t] = __expf(L[chunk * 64 + t] - MX);
    __syncthreads();

    if (t < V_) {
        float s = 0.f;
        #pragma unroll
        for (int j = 0; j < 8; ++j) s += lds[j][t];
        atomicAdd(&o[h * V_ + t], s);
    }
    if (t == 0) {
        float s = 0.f;
        #pragma unroll
        for (int j = 0; j < 64; ++j) s += rsum[j];
        atomicAdd(&S[h], s);
    }
}

// ---------------------------------------------------------------------------
// Kernel E: output projection with deferred softmax normalization.
//   y[d] += sum_v (o[h,v]/S[h]) * Wo[h,v,d]
// grid (16 d-chunks of 256, 32 heads, 2 v-halves), block 256 (4 waves).
// ---------------------------------------------------------------------------
__global__ void yproj_kernel(const float* __restrict__ Wo,
                             const float* __restrict__ o,
                             const float* __restrict__ S,
                             float* __restrict__ y) {
    const int chunk = blockIdx.x;   // 0..15: 256 d each
    const int h     = blockIdx.y;
    const int vhalf = blockIdx.z;   // 0..1: 64 v each
    const int t     = threadIdx.x;  // 256
    const int wv    = t >> 6;       // wave 0..3
    const int ln    = t & 63;       // lane -> d offset

    __shared__ float s_inv;
    __shared__ float os[V_ / 2];
    if (t == 0) s_inv = 1.f / S[h];
    __syncthreads();
    if (t < 64) os[t] = o[h * V_ + vhalf * 64 + t] * s_inv;
    __syncthreads();

    const int d0 = chunk * 256 + ln * 4;
    const float* Wh = Wo + (size_t)h * V_ * D_ + (size_t)vhalf * 64 * D_;

    f32x4 acc = {0.f, 0.f, 0.f, 0.f};
    const int v0 = wv * 16;
    #pragma unroll
    for (int v = 0; v < 16; ++v)
        acc += os[v0 + v] * ntload4(&Wh[(size_t)(v0 + v) * D_ + d0]);

    __shared__ f32x4 red4[4][64];
    red4[wv][ln] = acc;
    __syncthreads();
    if (t < 64) {
        const f32x4 s = red4[0][t] + red4[1][t] + red4[2][t] + red4[3][t];
        const int d = chunk * 256 + t * 4;
        atomicAdd(&y[d + 0], s.x);
        atomicAdd(&y[d + 1], s.y);
        atomicAdd(&y[d + 2], s.z);
        atomicAdd(&y[d + 3], s.w);
    }
}

// ---------------------------------------------------------------------------
extern "C" void kernel_launch(void* const* d_in, const int* in_sizes, int n_in,
                              void* d_out, int out_size, void* d_ws, size_t ws_size,
                              hipStream_t stream) {
    const float* x      = (const float*)d_in[0];
    const float* prev_K = (const float*)d_in[1];
    const float* prev_V = (const float*)d_in[2];
    const float* Wq     = (const float*)d_in[3];
    const float* Wk     = (const float*)d_in[4];
    const float* Wv     = (const float*)d_in[5];
    const float* Wo     = (const float*)d_in[6];

    float* out = (float*)d_out;
    float* y   = out;                                  // [D]
    float* Kc  = out + D_;                             // [H][MC][K]
    float* Vc  = Kc + (size_t)H_ * MC_ * K_;           // [H][MC][V]

    // workspace (floats): part[3][H][NCH][K], o[H][V], S[H], mx[H], lg[H][MC]
    float* ws   = (float*)d_ws;
    float* part = ws;                                  // 196608
    float* ov   = part + (size_t)3 * H_ * NCH_ * K_;   // 4096
    float* Sd   = ov + H_ * V_;                        // 32
    float* mxd  = Sd + H_;                             // 32
    float* lg   = mxd + H_;                            // 262144

    // no memsets needed: part written non-atomically by proj; mx init in
    // proj; o/S zeroed in B; y zeroed in D.
    proj_kernel        <<<dim3(NCH_, H_, 3), 256, 0, stream>>>(x, Wq, Wk, Wv, part, mxd);
    copyK_logits_kernel<<<dim3(128, H_),     256, 0, stream>>>(prev_K, part, Kc, lg, mxd, ov, Sd);
    copyV_out_kernel   <<<dim3(128, H_),     256, 0, stream>>>(prev_V, part, lg, mxd, Vc, ov, Sd, y);
    yproj_kernel       <<<dim3(16, H_, 2),   256, 0, stream>>>(Wo, ov, Sd, y);
}

// Round 7
// 148.104 us; speedup vs baseline: 1.2850x; 1.2850x over previous
//
#include <hip/hip_runtime.h>
#include <hip/hip_bf16.h>
#include <math.h>

#define H_  32
#define D_  4096
#define K_  128
#define V_  128
#define M_  8191     // prev cache length
#define MC_ 8192     // cache length after append
#define NCHUNK_ 64   // attention chunks per head (128 rows each)

typedef float f32x4 __attribute__((ext_vector_type(4)));

__device__ inline f32x4 ntload4(const float* p) {
    return __builtin_nontemporal_load((const f32x4*)p);
}
__device__ inline void ntstore4(float* p, f32x4 v) {
    __builtin_nontemporal_store(v, (f32x4*)p);
}

// ---------------------------------------------------------------------------
// Kernel A: q/k_new/v_new projections.  q[h,k] = sum_d x[d] * W[h,d,k]
// grid (32 d-chunks of 128, 32 heads, 3 projections), block 256.
// Partials atomically accumulated into qkv (pre-zeroed by memset).
// (Proven R5 structure, unchanged.)
// ---------------------------------------------------------------------------
__global__ void proj_kernel(const float* __restrict__ x,
                            const float* __restrict__ Wq,
                            const float* __restrict__ Wk,
                            const float* __restrict__ Wv,
                            float* __restrict__ qkv /* [3][H][K] */) {
    const int chunk = blockIdx.x;   // 0..31, 128 d each
    const int h     = blockIdx.y;
    const int proj  = blockIdx.z;
    const float* W  = (proj == 0) ? Wq : ((proj == 1) ? Wk : Wv);
    float* dst      = qkv + proj * (H_ * K_) + h * K_;

    const int t   = threadIdx.x;    // 256
    const int grp = t >> 5;         // 0..7
    const int cl  = t & 31;         // float4 column lane

    __shared__ float xs[128];
    if (t < 128) xs[t] = x[chunk * 128 + t];
    __syncthreads();

    const float* Wh = W + (size_t)h * D_ * K_ + (size_t)chunk * 128 * K_;

    f32x4 acc = {0.f, 0.f, 0.f, 0.f};
    #pragma unroll 4
    for (int r = grp; r < 128; r += 8) {
        const f32x4 v4 = ntload4(&Wh[(size_t)r * K_ + cl * 4]);
        acc += xs[r] * v4;
    }

    __shared__ float lds[8][K_];
    *(f32x4*)&lds[grp][cl * 4] = acc;
    __syncthreads();
    if (t < K_) {
        float s = 0.f;
        #pragma unroll
        for (int j = 0; j < 8; ++j) s += lds[j][t];
        atomicAdd(&dst[t], s);
    }
}

// ---------------------------------------------------------------------------
// Kernel BD: fused K-copy + logits + LOCAL softmax + V-copy + o-partials.
// Per block: 128 K-rows streamed (copy + dot with q -> pbuf), local max and
// exp-weights in LDS, then 128 V-rows streamed (copy + ebuf-weighted sum).
// Writes per-chunk (mx_b, S_b, o_b[128]) -- no global max dependency.
// Row M sources k_new/v_new from qkv.  grid (64 chunks, 32 heads), block 256.
// ---------------------------------------------------------------------------
__global__ __launch_bounds__(256) void attn_fused_kernel(
        const float* __restrict__ prev_K,
        const float* __restrict__ prev_V,
        const float* __restrict__ qkv,
        float* __restrict__ Kc,
        float* __restrict__ Vc,
        float* __restrict__ obuf /* [H][NCHUNK][V] */,
        float* __restrict__ mxb  /* [H][NCHUNK] */,
        float* __restrict__ sb   /* [H][NCHUNK] */) {
    const int chunk = blockIdx.x;   // 0..63, 128 rows each
    const int h     = blockIdx.y;
    const int t     = threadIdx.x;
    const int grp   = t >> 5;       // 0..7
    const int cl    = t & 31;       // float4 column lane

    const float* q  = qkv + h * K_;
    const float* kn = qkv + H_ * K_ + h * K_;
    const float* vn = qkv + 2 * H_ * K_ + h * K_;
    const f32x4 q4  = *(const f32x4*)&q[cl * 4];

    const float* Ksrc = prev_K + (size_t)h * M_ * K_;
    float*       Kd   = Kc     + (size_t)h * MC_ * K_;

    __shared__ float pbuf[128][33];   // dot partials; later reused as vred

    #pragma unroll
    for (int r = 0; r < 16; ++r) {
        const int ml = r * 8 + grp;          // local row 0..127
        const int m  = chunk * 128 + ml;
        f32x4 v4;
        if (m != M_) v4 = ntload4(&Ksrc[(size_t)m * K_ + cl * 4]);
        else         v4 = *(const f32x4*)&kn[cl * 4];
        ntstore4(&Kd[(size_t)m * K_ + cl * 4], v4);
        const f32x4 p4 = v4 * q4;
        pbuf[ml][cl] = p4.x + p4.y + p4.z + p4.w;
    }
    __syncthreads();

    __shared__ float lrow[128];
    __shared__ float red[128];
    if (t < 128) {
        float s = 0.f;
        #pragma unroll
        for (int j = 0; j < 32; ++j) s += pbuf[t][j];
        lrow[t] = s;
        red[t]  = s;
    }
    __syncthreads();
    for (int s = 64; s > 0; s >>= 1) {
        if (t < s) red[t] = fmaxf(red[t], red[t + s]);
        __syncthreads();
    }
    const float lmax = red[0];
    __syncthreads();

    __shared__ float ebuf[128];
    if (t < 128) {
        const float e = __expf(lrow[t] - lmax);
        ebuf[t] = e;
        red[t]  = e;
    }
    __syncthreads();
    for (int s = 64; s > 0; s >>= 1) {
        if (t < s) red[t] += red[t + s];
        __syncthreads();
    }
    if (t == 0) {
        mxb[h * NCHUNK_ + chunk] = lmax;
        sb [h * NCHUNK_ + chunk] = red[0];
    }

    // ---- V phase: copy + ebuf-weighted accumulate ----
    const float* Vsrc = prev_V + (size_t)h * M_ * V_;
    float*       Vd   = Vc     + (size_t)h * MC_ * V_;

    f32x4 acc = {0.f, 0.f, 0.f, 0.f};
    #pragma unroll
    for (int r = 0; r < 16; ++r) {
        const int ml = r * 8 + grp;
        const int m  = chunk * 128 + ml;
        f32x4 v4;
        if (m != M_) v4 = ntload4(&Vsrc[(size_t)m * V_ + cl * 4]);
        else         v4 = *(const f32x4*)&vn[cl * 4];
        ntstore4(&Vd[(size_t)m * V_ + cl * 4], v4);
        acc += ebuf[ml] * v4;
    }
    __syncthreads();                         // pbuf fully consumed; reuse
    float (*vred)[V_] = (float (*)[V_])pbuf;
    *(f32x4*)&vred[grp][cl * 4] = acc;
    __syncthreads();
    if (t < V_) {
        float s = 0.f;
        #pragma unroll
        for (int j = 0; j < 8; ++j) s += vred[j][t];
        obuf[((size_t)h * NCHUNK_ + chunk) * V_ + t] = s;
    }
}

// ---------------------------------------------------------------------------
// Kernel C2: combine per-chunk partials.  MX = max_c mx_c;
//   o[h,v] = sum_c e^{mx_c-MX} o_c[v];  S[h] = sum_c e^{mx_c-MX} S_c.
// Also zeroes y (completes before kernel E's atomics).  grid 32, block 128.
// ---------------------------------------------------------------------------
__global__ void combine_kernel(const float* __restrict__ obuf,
                               const float* __restrict__ mxb,
                               const float* __restrict__ sb,
                               float* __restrict__ o /* [H][V] */,
                               float* __restrict__ S /* [H] */,
                               float* __restrict__ y /* [D] */) {
    const int h = blockIdx.x;
    const int t = threadIdx.x;  // 128

    y[h * 128 + t] = 0.f;

    __shared__ float smx[NCHUNK_];
    __shared__ float sexp[NCHUNK_];
    __shared__ float red[NCHUNK_];
    if (t < NCHUNK_) { smx[t] = mxb[h * NCHUNK_ + t]; red[t] = smx[t]; }
    __syncthreads();
    for (int s = NCHUNK_ / 2; s > 0; s >>= 1) {
        if (t < s) red[t] = fmaxf(red[t], red[t + s]);
        __syncthreads();
    }
    const float MX = red[0];
    __syncthreads();
    if (t < NCHUNK_) sexp[t] = __expf(smx[t] - MX);
    __syncthreads();

    const float* ob = obuf + (size_t)h * NCHUNK_ * V_;
    float acc = 0.f;
    #pragma unroll 8
    for (int c = 0; c < NCHUNK_; ++c) acc += sexp[c] * ob[c * V_ + t];
    o[h * V_ + t] = acc;

    if (t == 0) {
        float s = 0.f;
        #pragma unroll
        for (int c = 0; c < NCHUNK_; ++c) s += sexp[c] * sb[h * NCHUNK_ + c];
        S[h] = s;
    }
}

// ---------------------------------------------------------------------------
// Kernel E: output projection with deferred softmax normalization.
//   y[d] += sum_v (o[h,v]/S[h]) * Wo[h,v,d]
// grid (16 d-chunks of 256, 32 heads, 2 v-halves), block 256 (4 waves).
// (Proven R5 structure, unchanged.)
// ---------------------------------------------------------------------------
__global__ void yproj_kernel(const float* __restrict__ Wo,
                             const float* __restrict__ o,
                             const float* __restrict__ S,
                             float* __restrict__ y) {
    const int chunk = blockIdx.x;   // 0..15: 256 d each
    const int h     = blockIdx.y;
    const int vhalf = blockIdx.z;   // 0..1: 64 v each
    const int t     = threadIdx.x;  // 256
    const int wv    = t >> 6;       // wave 0..3
    const int ln    = t & 63;       // lane -> d offset

    __shared__ float s_inv;
    __shared__ float os[V_ / 2];
    if (t == 0) s_inv = 1.f / S[h];
    __syncthreads();
    if (t < 64) os[t] = o[h * V_ + vhalf * 64 + t] * s_inv;
    __syncthreads();

    const int d0 = chunk * 256 + ln * 4;
    const float* Wh = Wo + (size_t)h * V_ * D_ + (size_t)vhalf * 64 * D_;

    f32x4 acc = {0.f, 0.f, 0.f, 0.f};
    const int v0 = wv * 16;
    #pragma unroll
    for (int v = 0; v < 16; ++v)
        acc += os[v0 + v] * ntload4(&Wh[(size_t)(v0 + v) * D_ + d0]);

    __shared__ f32x4 red4[4][64];
    red4[wv][ln] = acc;
    __syncthreads();
    if (t < 64) {
        const f32x4 s = red4[0][t] + red4[1][t] + red4[2][t] + red4[3][t];
        const int d = chunk * 256 + t * 4;
        atomicAdd(&y[d + 0], s.x);
        atomicAdd(&y[d + 1], s.y);
        atomicAdd(&y[d + 2], s.z);
        atomicAdd(&y[d + 3], s.w);
    }
}

// ---------------------------------------------------------------------------
extern "C" void kernel_launch(void* const* d_in, const int* in_sizes, int n_in,
                              void* d_out, int out_size, void* d_ws, size_t ws_size,
                              hipStream_t stream) {
    const float* x      = (const float*)d_in[0];
    const float* prev_K = (const float*)d_in[1];
    const float* prev_V = (const float*)d_in[2];
    const float* Wq     = (const float*)d_in[3];
    const float* Wk     = (const float*)d_in[4];
    const float* Wv     = (const float*)d_in[5];
    const float* Wo     = (const float*)d_in[6];

    float* out = (float*)d_out;
    float* y   = out;                                  // [D]
    float* Kc  = out + D_;                             // [H][MC][K]
    float* Vc  = Kc + (size_t)H_ * MC_ * K_;           // [H][MC][V]

    // workspace (floats): qkv[3][H][K], obuf[H][64][V], mxb, sb, o[H][V], S[H]
    float* ws   = (float*)d_ws;
    float* qkv  = ws;                                    // 12288
    float* obuf = qkv + 3 * H_ * K_;                     // 262144
    float* mxb  = obuf + (size_t)H_ * NCHUNK_ * V_;      // 2048
    float* sb   = mxb + H_ * NCHUNK_;                    // 2048
    float* ov   = sb + H_ * NCHUNK_;                     // 4096
    float* Sd   = ov + H_ * V_;                          // 32

    // only qkv needs pre-zero (proj atomicAdds into it)
    hipMemsetAsync(qkv, 0, (size_t)3 * H_ * K_ * sizeof(float), stream);

    proj_kernel      <<<dim3(32, H_, 3),    256, 0, stream>>>(x, Wq, Wk, Wv, qkv);
    attn_fused_kernel<<<dim3(NCHUNK_, H_),  256, 0, stream>>>(prev_K, prev_V, qkv,
                                                              Kc, Vc, obuf, mxb, sb);
    combine_kernel   <<<H_,                 128, 0, stream>>>(obuf, mxb, sb, ov, Sd, y);
    yproj_kernel     <<<dim3(16, H_, 2),    256, 0, stream>>>(Wo, ov, Sd, y);
}

// Round 8
// 145.891 us; speedup vs baseline: 1.3045x; 1.0152x over previous
//
#include <hip/hip_runtime.h>
#include <hip/hip_bf16.h>
#include <math.h>

#define H_  32
#define D_  4096
#define K_  128
#define V_  128
#define M_  8191     // prev cache length
#define MC_ 8192     // cache length after append
#define NCHUNK_ 64   // attention chunks per head (128 rows each)

typedef float f32x4 __attribute__((ext_vector_type(4)));

__device__ inline f32x4 ntload4(const float* p) {
    return __builtin_nontemporal_load((const f32x4*)p);
}
__device__ inline void ntstore4(float* p, f32x4 v) {
    __builtin_nontemporal_store(v, (f32x4*)p);
}

// ---------------------------------------------------------------------------
// Kernel A: q/k_new/v_new projections.  q[h,k] = sum_d x[d] * W[h,d,k]
// grid (32 d-chunks of 128, 32 heads, 3 projections), block 256.
// Partials atomically accumulated into qkv (pre-zeroed by memset).
// ---------------------------------------------------------------------------
__global__ void proj_kernel(const float* __restrict__ x,
                            const float* __restrict__ Wq,
                            const float* __restrict__ Wk,
                            const float* __restrict__ Wv,
                            float* __restrict__ qkv /* [3][H][K] */) {
    const int chunk = blockIdx.x;   // 0..31, 128 d each
    const int h     = blockIdx.y;
    const int proj  = blockIdx.z;
    const float* W  = (proj == 0) ? Wq : ((proj == 1) ? Wk : Wv);
    float* dst      = qkv + proj * (H_ * K_) + h * K_;

    const int t   = threadIdx.x;    // 256
    const int grp = t >> 5;         // 0..7
    const int cl  = t & 31;         // float4 column lane

    __shared__ float xs[128];
    if (t < 128) xs[t] = x[chunk * 128 + t];
    __syncthreads();

    const float* Wh = W + (size_t)h * D_ * K_ + (size_t)chunk * 128 * K_;

    f32x4 acc = {0.f, 0.f, 0.f, 0.f};
    #pragma unroll 4
    for (int r = grp; r < 128; r += 8) {
        const f32x4 v4 = ntload4(&Wh[(size_t)r * K_ + cl * 4]);
        acc += xs[r] * v4;
    }

    __shared__ float lds[8][K_];
    *(f32x4*)&lds[grp][cl * 4] = acc;
    __syncthreads();
    if (t < K_) {
        float s = 0.f;
        #pragma unroll
        for (int j = 0; j < 8; ++j) s += lds[j][t];
        atomicAdd(&dst[t], s);
    }
}

// ---------------------------------------------------------------------------
// Kernel BD: fused K-copy + logits + LOCAL softmax + V-copy + o-partials.
// Per block: 128 K-rows streamed (copy + dot with q -> pbuf), local max and
// exp-weights in LDS, then 128 V-rows streamed (copy + ebuf-weighted sum).
// Writes per-chunk (mx_b, S_b, o_b[128]) -- no global max dependency.
// Row M sources k_new/v_new from qkv.  Chunk-0 blocks also zero y.
// grid (64 chunks, 32 heads), block 256.
// ---------------------------------------------------------------------------
__global__ __launch_bounds__(256) void attn_fused_kernel(
        const float* __restrict__ prev_K,
        const float* __restrict__ prev_V,
        const float* __restrict__ qkv,
        float* __restrict__ Kc,
        float* __restrict__ Vc,
        float* __restrict__ obuf /* [H][NCHUNK][V] */,
        float* __restrict__ mxb  /* [H][NCHUNK] */,
        float* __restrict__ sb   /* [H][NCHUNK] */,
        float* __restrict__ y    /* [D] */) {
    const int chunk = blockIdx.x;   // 0..63, 128 rows each
    const int h     = blockIdx.y;
    const int t     = threadIdx.x;
    const int grp   = t >> 5;       // 0..7
    const int cl    = t & 31;       // float4 column lane

    if (chunk == 0 && t < 128) y[h * 128 + t] = 0.f;

    const float* q  = qkv + h * K_;
    const float* kn = qkv + H_ * K_ + h * K_;
    const float* vn = qkv + 2 * H_ * K_ + h * K_;
    const f32x4 q4  = *(const f32x4*)&q[cl * 4];

    const float* Ksrc = prev_K + (size_t)h * M_ * K_;
    float*       Kd   = Kc     + (size_t)h * MC_ * K_;

    __shared__ float pbuf[128][33];   // dot partials; later reused as vred

    #pragma unroll
    for (int r = 0; r < 16; ++r) {
        const int ml = r * 8 + grp;          // local row 0..127
        const int m  = chunk * 128 + ml;
        f32x4 v4;
        if (m != M_) v4 = ntload4(&Ksrc[(size_t)m * K_ + cl * 4]);
        else         v4 = *(const f32x4*)&kn[cl * 4];
        ntstore4(&Kd[(size_t)m * K_ + cl * 4], v4);
        const f32x4 p4 = v4 * q4;
        pbuf[ml][cl] = p4.x + p4.y + p4.z + p4.w;
    }
    __syncthreads();

    __shared__ float lrow[128];
    __shared__ float red[128];
    if (t < 128) {
        float s = 0.f;
        #pragma unroll
        for (int j = 0; j < 32; ++j) s += pbuf[t][j];
        lrow[t] = s;
        red[t]  = s;
    }
    __syncthreads();
    for (int s = 64; s > 0; s >>= 1) {
        if (t < s) red[t] = fmaxf(red[t], red[t + s]);
        __syncthreads();
    }
    const float lmax = red[0];
    __syncthreads();

    __shared__ float ebuf[128];
    if (t < 128) {
        const float e = __expf(lrow[t] - lmax);
        ebuf[t] = e;
        red[t]  = e;
    }
    __syncthreads();
    for (int s = 64; s > 0; s >>= 1) {
        if (t < s) red[t] += red[t + s];
        __syncthreads();
    }
    if (t == 0) {
        mxb[h * NCHUNK_ + chunk] = lmax;
        sb [h * NCHUNK_ + chunk] = red[0];
    }

    // ---- V phase: copy + ebuf-weighted accumulate ----
    const float* Vsrc = prev_V + (size_t)h * M_ * V_;
    float*       Vd   = Vc     + (size_t)h * MC_ * V_;

    f32x4 acc = {0.f, 0.f, 0.f, 0.f};
    #pragma unroll
    for (int r = 0; r < 16; ++r) {
        const int ml = r * 8 + grp;
        const int m  = chunk * 128 + ml;
        f32x4 v4;
        if (m != M_) v4 = ntload4(&Vsrc[(size_t)m * V_ + cl * 4]);
        else         v4 = *(const f32x4*)&vn[cl * 4];
        ntstore4(&Vd[(size_t)m * V_ + cl * 4], v4);
        acc += ebuf[ml] * v4;
    }
    __syncthreads();                         // pbuf fully consumed; reuse
    float (*vred)[V_] = (float (*)[V_])pbuf;
    *(f32x4*)&vred[grp][cl * 4] = acc;
    __syncthreads();
    if (t < V_) {
        float s = 0.f;
        #pragma unroll
        for (int j = 0; j < 8; ++j) s += vred[j][t];
        obuf[((size_t)h * NCHUNK_ + chunk) * V_ + t] = s;
    }
}

// ---------------------------------------------------------------------------
// Kernel E: output projection with INLINE combine + deferred normalization.
// Prologue (per block): MX = max_c mxb[h,c]; sexp[c] = e^{mxb-MX};
//   S = sum_c sexp[c]*sb[h,c];  os[v] = (sum_c sexp[c]*obuf[h,c,v]) / S.
// Main: y[d] += sum_v os[v] * Wo[h,v,d].
// grid (16 d-chunks of 256, 32 heads, 2 v-halves), block 256 (4 waves).
// ---------------------------------------------------------------------------
__global__ void yproj_kernel(const float* __restrict__ Wo,
                             const float* __restrict__ obuf,
                             const float* __restrict__ mxb,
                             const float* __restrict__ sb,
                             float* __restrict__ y) {
    const int chunk = blockIdx.x;   // 0..15: 256 d each
    const int h     = blockIdx.y;
    const int vhalf = blockIdx.z;   // 0..1: 64 v each
    const int t     = threadIdx.x;  // 256
    const int wv    = t >> 6;       // wave 0..3
    const int ln    = t & 63;       // lane

    __shared__ float sexp[NCHUNK_];
    __shared__ float s_inv;
    __shared__ float os[V_ / 2];
    __shared__ float part[4][64];

    // wave 0: combine scalars via shuffle (64 lanes = 64 chunks)
    if (wv == 0) {
        const float m = mxb[h * NCHUNK_ + ln];
        float mm = m;
        #pragma unroll
        for (int off = 32; off > 0; off >>= 1)
            mm = fmaxf(mm, __shfl_xor(mm, off));
        const float e = __expf(m - mm);
        sexp[ln] = e;
        float s = e * sb[h * NCHUNK_ + ln];
        #pragma unroll
        for (int off = 32; off > 0; off >>= 1)
            s += __shfl_xor(s, off);
        if (ln == 0) s_inv = 1.f / s;
    }
    __syncthreads();

    // all 4 waves: os[v] = sum_c sexp[c] * obuf[h,c,vhalf*64+v]
    {
        const float* ob = obuf + (size_t)h * NCHUNK_ * V_ + vhalf * 64 + (t & 63);
        const int c0 = wv * 16;
        float a = 0.f;
        #pragma unroll
        for (int c = 0; c < 16; ++c) a += sexp[c0 + c] * ob[(c0 + c) * V_];
        part[wv][t & 63] = a;
    }
    __syncthreads();
    if (t < 64)
        os[t] = (part[0][t] + part[1][t] + part[2][t] + part[3][t]) * s_inv;
    __syncthreads();

    const int d0 = chunk * 256 + ln * 4;
    const float* Wh = Wo + (size_t)h * V_ * D_ + (size_t)vhalf * 64 * D_;

    f32x4 acc = {0.f, 0.f, 0.f, 0.f};
    const int v0 = wv * 16;
    #pragma unroll
    for (int v = 0; v < 16; ++v)
        acc += os[v0 + v] * ntload4(&Wh[(size_t)(v0 + v) * D_ + d0]);

    __shared__ f32x4 red4[4][64];
    red4[wv][ln] = acc;
    __syncthreads();
    if (t < 64) {
        const f32x4 s = red4[0][t] + red4[1][t] + red4[2][t] + red4[3][t];
        const int d = chunk * 256 + t * 4;
        atomicAdd(&y[d + 0], s.x);
        atomicAdd(&y[d + 1], s.y);
        atomicAdd(&y[d + 2], s.z);
        atomicAdd(&y[d + 3], s.w);
    }
}

// ---------------------------------------------------------------------------
extern "C" void kernel_launch(void* const* d_in, const int* in_sizes, int n_in,
                              void* d_out, int out_size, void* d_ws, size_t ws_size,
                              hipStream_t stream) {
    const float* x      = (const float*)d_in[0];
    const float* prev_K = (const float*)d_in[1];
    const float* prev_V = (const float*)d_in[2];
    const float* Wq     = (const float*)d_in[3];
    const float* Wk     = (const float*)d_in[4];
    const float* Wv     = (const float*)d_in[5];
    const float* Wo     = (const float*)d_in[6];

    float* out = (float*)d_out;
    float* y   = out;                                  // [D]
    float* Kc  = out + D_;                             // [H][MC][K]
    float* Vc  = Kc + (size_t)H_ * MC_ * K_;           // [H][MC][V]

    // workspace (floats): qkv[3][H][K], obuf[H][64][V], mxb, sb
    float* ws   = (float*)d_ws;
    float* qkv  = ws;                                    // 12288
    float* obuf = qkv + 3 * H_ * K_;                     // 262144
    float* mxb  = obuf + (size_t)H_ * NCHUNK_ * V_;      // 2048
    float* sb   = mxb + H_ * NCHUNK_;                    // 2048

    // only qkv needs pre-zero (proj atomicAdds into it)
    hipMemsetAsync(qkv, 0, (size_t)3 * H_ * K_ * sizeof(float), stream);

    proj_kernel      <<<dim3(32, H_, 3),   256, 0, stream>>>(x, Wq, Wk, Wv, qkv);
    attn_fused_kernel<<<dim3(NCHUNK_, H_), 256, 0, stream>>>(prev_K, prev_V, qkv,
                                                             Kc, Vc, obuf, mxb, sb, y);
    yproj_kernel     <<<dim3(16, H_, 2),   256, 0, stream>>>(Wo, obuf, mxb, sb, y);
}

// Round 9
// 143.132 us; speedup vs baseline: 1.3297x; 1.0193x over previous
//
#include <hip/hip_runtime.h>
#include <hip/hip_bf16.h>
#include <math.h>

#define H_  32
#define D_  4096
#define K_  128
#define V_  128
#define M_  8191     // prev cache length
#define MC_ 8192     // cache length after append
#define NCHUNK_ 64   // attention chunks per head (128 rows each)

typedef float f32x4 __attribute__((ext_vector_type(4)));

__device__ inline f32x4 ntload4(const float* p) {          // stream, don't retain
    return __builtin_nontemporal_load((const f32x4*)p);
}
__device__ inline f32x4 ld4(const float* p) {              // normal, L3-retained
    return *(const f32x4*)p;
}
__device__ inline void ntstore4(float* p, f32x4 v) {
    __builtin_nontemporal_store(v, (f32x4*)p);
}

// ---------------------------------------------------------------------------
// Kernel A: q/k_new/v_new projections.  q[h,k] = sum_d x[d] * W[h,d,k]
// grid (32 d-chunks of 128, 32 heads, 3 projections), block 256.
// W loads stay NONTEMPORAL (read-once stream; don't evict KV from L3).
// ---------------------------------------------------------------------------
__global__ void proj_kernel(const float* __restrict__ x,
                            const float* __restrict__ Wq,
                            const float* __restrict__ Wk,
                            const float* __restrict__ Wv,
                            float* __restrict__ qkv /* [3][H][K] */) {
    const int chunk = blockIdx.x;   // 0..31, 128 d each
    const int h     = blockIdx.y;
    const int proj  = blockIdx.z;
    const float* W  = (proj == 0) ? Wq : ((proj == 1) ? Wk : Wv);
    float* dst      = qkv + proj * (H_ * K_) + h * K_;

    const int t   = threadIdx.x;    // 256
    const int grp = t >> 5;         // 0..7
    const int cl  = t & 31;         // float4 column lane

    __shared__ float xs[128];
    if (t < 128) xs[t] = x[chunk * 128 + t];
    __syncthreads();

    const float* Wh = W + (size_t)h * D_ * K_ + (size_t)chunk * 128 * K_;

    f32x4 acc = {0.f, 0.f, 0.f, 0.f};
    #pragma unroll 4
    for (int r = grp; r < 128; r += 8) {
        const f32x4 v4 = ntload4(&Wh[(size_t)r * K_ + cl * 4]);
        acc += xs[r] * v4;
    }

    __shared__ float lds[8][K_];
    *(f32x4*)&lds[grp][cl * 4] = acc;
    __syncthreads();
    if (t < K_) {
        float s = 0.f;
        #pragma unroll
        for (int j = 0; j < 8; ++j) s += lds[j][t];
        atomicAdd(&dst[t], s);
    }
}

// ---------------------------------------------------------------------------
// Kernel BD: fused K-copy + logits + LOCAL softmax + V-copy + o-partials.
// prev_K/prev_V loads are PLAIN (L3-retained across graph replays).
// Kc/Vc stores are nontemporal.  Wave-shuffle reduces (4 barriers total).
// Hot loops branch-free except in the single chunk containing row M.
// grid (64 chunks, 32 heads), block 256.
// ---------------------------------------------------------------------------
__global__ __launch_bounds__(256) void attn_fused_kernel(
        const float* __restrict__ prev_K,
        const float* __restrict__ prev_V,
        const float* __restrict__ qkv,
        float* __restrict__ Kc,
        float* __restrict__ Vc,
        float* __restrict__ obuf /* [H][NCHUNK][V] */,
        float* __restrict__ mxb  /* [H][NCHUNK] */,
        float* __restrict__ sb   /* [H][NCHUNK] */,
        float* __restrict__ y    /* [D] */) {
    const int chunk = blockIdx.x;   // 0..63, 128 rows each
    const int h     = blockIdx.y;
    const int t     = threadIdx.x;
    const int grp   = t >> 5;       // 0..7
    const int cl    = t & 31;       // float4 column lane
    const int lane  = t & 63;

    if (chunk == 0 && t < 128) y[h * 128 + t] = 0.f;

    const float* q  = qkv + h * K_;
    const float* kn = qkv + H_ * K_ + h * K_;
    const float* vn = qkv + 2 * H_ * K_ + h * K_;
    const f32x4 q4  = *(const f32x4*)&q[cl * 4];

    const float* Ksrc = prev_K + (size_t)h * M_ * K_;
    float*       Kd   = Kc     + (size_t)h * MC_ * K_;

    __shared__ float pbuf[128][33];   // dot partials; later reused as vred
    __shared__ float lrow[128];
    __shared__ float ebuf[128];
    __shared__ float s_mx;

    // ---- K phase: copy + dot partials ----
    if (chunk != NCHUNK_ - 1) {
        #pragma unroll
        for (int r = 0; r < 16; ++r) {
            const int ml = r * 8 + grp;
            const int m  = chunk * 128 + ml;
            const f32x4 v4 = ld4(&Ksrc[(size_t)m * K_ + cl * 4]);
            ntstore4(&Kd[(size_t)m * K_ + cl * 4], v4);
            const f32x4 p4 = v4 * q4;
            pbuf[ml][cl] = p4.x + p4.y + p4.z + p4.w;
        }
    } else {
        #pragma unroll
        for (int r = 0; r < 16; ++r) {
            const int ml = r * 8 + grp;
            const int m  = chunk * 128 + ml;
            f32x4 v4;
            if (m != M_) v4 = ld4(&Ksrc[(size_t)m * K_ + cl * 4]);
            else         v4 = *(const f32x4*)&kn[cl * 4];
            ntstore4(&Kd[(size_t)m * K_ + cl * 4], v4);
            const f32x4 p4 = v4 * q4;
            pbuf[ml][cl] = p4.x + p4.y + p4.z + p4.w;
        }
    }
    __syncthreads();                                   // (1) pbuf ready

    if (t < 128) {
        float s = 0.f;
        #pragma unroll
        for (int j = 0; j < 32; ++j) s += pbuf[t][j];
        lrow[t] = s;
    }
    __syncthreads();                                   // (2) lrow ready

    if (t < 64) {                                      // wave 0: max via shuffle
        float mm = fmaxf(lrow[lane], lrow[lane + 64]);
        #pragma unroll
        for (int off = 32; off > 0; off >>= 1)
            mm = fmaxf(mm, __shfl_xor(mm, off));
        if (lane == 0) s_mx = mm;
    }
    __syncthreads();                                   // (3) s_mx ready

    if (t < 128) ebuf[t] = __expf(lrow[t] - s_mx);
    __syncthreads();                                   // (4) ebuf ready

    if (t >= 64 && t < 128) {                          // wave 1 (low half): sum
        float s = ebuf[lane] + ebuf[lane + 64];
        #pragma unroll
        for (int off = 32; off > 0; off >>= 1)
            s += __shfl_xor(s, off);
        if (lane == 0) {
            mxb[h * NCHUNK_ + chunk] = s_mx;
            sb [h * NCHUNK_ + chunk] = s;
        }
    }

    // ---- V phase: copy + ebuf-weighted accumulate ----
    const float* Vsrc = prev_V + (size_t)h * M_ * V_;
    float*       Vd   = Vc     + (size_t)h * MC_ * V_;

    f32x4 acc = {0.f, 0.f, 0.f, 0.f};
    if (chunk != NCHUNK_ - 1) {
        #pragma unroll
        for (int r = 0; r < 16; ++r) {
            const int ml = r * 8 + grp;
            const int m  = chunk * 128 + ml;
            const f32x4 v4 = ld4(&Vsrc[(size_t)m * V_ + cl * 4]);
            ntstore4(&Vd[(size_t)m * V_ + cl * 4], v4);
            acc += ebuf[ml] * v4;
        }
    } else {
        #pragma unroll
        for (int r = 0; r < 16; ++r) {
            const int ml = r * 8 + grp;
            const int m  = chunk * 128 + ml;
            f32x4 v4;
            if (m != M_) v4 = ld4(&Vsrc[(size_t)m * V_ + cl * 4]);
            else         v4 = *(const f32x4*)&vn[cl * 4];
            ntstore4(&Vd[(size_t)m * V_ + cl * 4], v4);
            acc += ebuf[ml] * v4;
        }
    }
    __syncthreads();                                   // (5) pbuf reusable
    float (*vred)[V_] = (float (*)[V_])pbuf;
    *(f32x4*)&vred[grp][cl * 4] = acc;
    __syncthreads();                                   // (6) vred ready
    if (t < V_) {
        float s = 0.f;
        #pragma unroll
        for (int j = 0; j < 8; ++j) s += vred[j][t];
        obuf[((size_t)h * NCHUNK_ + chunk) * V_ + t] = s;
    }
}

// ---------------------------------------------------------------------------
// Kernel E: output projection with INLINE combine + deferred normalization.
// Wo loads nontemporal (read-once).  grid (16, 32, 2), block 256.
// ---------------------------------------------------------------------------
__global__ void yproj_kernel(const float* __restrict__ Wo,
                             const float* __restrict__ obuf,
                             const float* __restrict__ mxb,
                             const float* __restrict__ sb,
                             float* __restrict__ y) {
    const int chunk = blockIdx.x;   // 0..15: 256 d each
    const int h     = blockIdx.y;
    const int vhalf = blockIdx.z;   // 0..1: 64 v each
    const int t     = threadIdx.x;  // 256
    const int wv    = t >> 6;       // wave 0..3
    const int ln    = t & 63;       // lane

    __shared__ float sexp[NCHUNK_];
    __shared__ float s_inv;
    __shared__ float os[V_ / 2];
    __shared__ float part[4][64];

    // wave 0: combine scalars via shuffle (64 lanes = 64 chunks)
    if (wv == 0) {
        const float m = mxb[h * NCHUNK_ + ln];
        float mm = m;
        #pragma unroll
        for (int off = 32; off > 0; off >>= 1)
            mm = fmaxf(mm, __shfl_xor(mm, off));
        const float e = __expf(m - mm);
        sexp[ln] = e;
        float s = e * sb[h * NCHUNK_ + ln];
        #pragma unroll
        for (int off = 32; off > 0; off >>= 1)
            s += __shfl_xor(s, off);
        if (ln == 0) s_inv = 1.f / s;
    }
    __syncthreads();

    // all 4 waves: os[v] = sum_c sexp[c] * obuf[h,c,vhalf*64+v]
    {
        const float* ob = obuf + (size_t)h * NCHUNK_ * V_ + vhalf * 64 + ln;
        const int c0 = wv * 16;
        float a = 0.f;
        #pragma unroll
        for (int c = 0; c < 16; ++c) a += sexp[c0 + c] * ob[(c0 + c) * V_];
        part[wv][ln] = a;
    }
    __syncthreads();
    if (t < 64)
        os[t] = (part[0][t] + part[1][t] + part[2][t] + part[3][t]) * s_inv;
    __syncthreads();

    const int d0 = chunk * 256 + ln * 4;
    const float* Wh = Wo + (size_t)h * V_ * D_ + (size_t)vhalf * 64 * D_;

    f32x4 acc = {0.f, 0.f, 0.f, 0.f};
    const int v0 = wv * 16;
    #pragma unroll
    for (int v = 0; v < 16; ++v)
        acc += os[v0 + v] * ntload4(&Wh[(size_t)(v0 + v) * D_ + d0]);

    __shared__ f32x4 red4[4][64];
    red4[wv][ln] = acc;
    __syncthreads();
    if (t < 64) {
        const f32x4 s = red4[0][t] + red4[1][t] + red4[2][t] + red4[3][t];
        const int d = chunk * 256 + t * 4;
        atomicAdd(&y[d + 0], s.x);
        atomicAdd(&y[d + 1], s.y);
        atomicAdd(&y[d + 2], s.z);
        atomicAdd(&y[d + 3], s.w);
    }
}

// ---------------------------------------------------------------------------
extern "C" void kernel_launch(void* const* d_in, const int* in_sizes, int n_in,
                              void* d_out, int out_size, void* d_ws, size_t ws_size,
                              hipStream_t stream) {
    const float* x      = (const float*)d_in[0];
    const float* prev_K = (const float*)d_in[1];
    const float* prev_V = (const float*)d_in[2];
    const float* Wq     = (const float*)d_in[3];
    const float* Wk     = (const float*)d_in[4];
    const float* Wv     = (const float*)d_in[5];
    const float* Wo     = (const float*)d_in[6];

    float* out = (float*)d_out;
    float* y   = out;                                  // [D]
    float* Kc  = out + D_;                             // [H][MC][K]
    float* Vc  = Kc + (size_t)H_ * MC_ * K_;           // [H][MC][V]

    // workspace (floats): qkv[3][H][K], obuf[H][64][V], mxb, sb
    float* ws   = (float*)d_ws;
    float* qkv  = ws;                                    // 12288
    float* obuf = qkv + 3 * H_ * K_;                     // 262144
    float* mxb  = obuf + (size_t)H_ * NCHUNK_ * V_;      // 2048
    float* sb   = mxb + H_ * NCHUNK_;                    // 2048

    // only qkv needs pre-zero (proj atomicAdds into it)
    hipMemsetAsync(qkv, 0, (size_t)3 * H_ * K_ * sizeof(float), stream);

    proj_kernel      <<<dim3(32, H_, 3),   256, 0, stream>>>(x, Wq, Wk, Wv, qkv);
    attn_fused_kernel<<<dim3(NCHUNK_, H_), 256, 0, stream>>>(prev_K, prev_V, qkv,
                                                             Kc, Vc, obuf, mxb, sb, y);
    yproj_kernel     <<<dim3(16, H_, 2),   256, 0, stream>>>(Wo, obuf, mxb, sb, y);
}